// Round 16
// baseline (319.297 us; speedup 1.0000x reference)
//
#include <hip/hip_runtime.h>
#include <hip/hip_bf16.h>

// Problem constants
#define NB  2      // batch
#define CC  256    // channels
#define NHD 8      // heads
#define HD  32     // head dim
#define NT  4096   // tokens = H*W

typedef __bf16 bf16x8 __attribute__((ext_vector_type(8)));
typedef bf16x8 bf16x8_ma __attribute__((may_alias));
typedef __bf16 bf16x4 __attribute__((ext_vector_type(4)));
typedef bf16x4 bf16x4_ma __attribute__((may_alias));
typedef float  f32x4  __attribute__((ext_vector_type(4)));

static __device__ __forceinline__ f32x4 zero4() {
    f32x4 z = {0.f, 0.f, 0.f, 0.f}; return z;
}

// q pre-scale: log2(e) / sqrt(32)  (exp(s) == exp2(s * log2 e))
#define QSCALE 0.25505392421795654f

// ---------------------------------------------------------------------------
// ROUND 16: S-TRANSPOSED softmax. R15 showed attn_k is issue-bound on the
// per-element softmax path (18 DS ops + 16 cvt + shfl butterflies per tile),
// not occupancy-bound. Swapping the score MFMA operands (A=K, B=Q) makes the
// D-layout hold 4 CONSECUTIVE j per lane for a fixed query i = c16:
//   - P store: 16x ds_write_b16 -> 4x ds_write_b64 (packed bf16x4)
//   - l: one scalar per lane; shfl butterfly 4x5 -> 2 total
//   - K/Q loads and the whole PV stage are byte-identical
// Plus: qkv epilogue q/k stores packed bf16x4 (16 -> 12 stores).
// ---------------------------------------------------------------------------

// ---------------------------------------------------------------------------
// Kernel 0: f32 -> bf16 convert (weights).
// ---------------------------------------------------------------------------
__global__ __launch_bounds__(256) void convw_k(const float* __restrict__ src,
                                               __bf16* __restrict__ dst, int n) {
    const int i = blockIdx.x * 256 + threadIdx.x;
    if (i < n) dst[i] = (__bf16)src[i];
}

// ---------------------------------------------------------------------------
// Kernel 1: LDS-tiled transpose+convert x f32 [b][c][n] -> xt bf16 [b][n][c].
// ---------------------------------------------------------------------------
__global__ __launch_bounds__(256) void transpose_k(const float* __restrict__ x,
                                                   __bf16* __restrict__ xt) {
    __shared__ __bf16 T[64][65];
    const int tid = threadIdx.x;
    const int n0 = blockIdx.x * 64, c0 = blockIdx.y * 64, b = blockIdx.z;

#pragma unroll
    for (int rep = 0; rep < 16; ++rep) {
        const int e = rep * 256 + tid;
        const int cl = e >> 6, nl = e & 63;
        T[nl][cl] = (__bf16)x[((size_t)(b * CC + c0 + cl)) * NT + n0 + nl];
    }
    __syncthreads();
#pragma unroll
    for (int rep = 0; rep < 16; ++rep) {
        const int e = rep * 256 + tid;
        const int nl = e >> 6, cl = e & 63;
        xt[((size_t)(b * NT + n0 + nl)) * CC + c0 + cl] = T[nl][cl];
    }
}

// ---------------------------------------------------------------------------
// Kernel 2: QKV GEMM (MFMA). q pre-scaled by QSCALE. Packed q/k stores.
// qt/kt token-major [bh][n][32], vv d-major [bh][32][n].
// grid (NT/64, 768/64, NB), block 256.
// ---------------------------------------------------------------------------
__global__ __launch_bounds__(256) void qkv_k(const __bf16* __restrict__ wqkv,
                                             const __bf16* __restrict__ xt,
                                             __bf16* __restrict__ qt,
                                             __bf16* __restrict__ kt,
                                             __bf16* __restrict__ vv) {
    const int lane = threadIdx.x & 63, wv = threadIdx.x >> 6;
    const int g = lane >> 4, c16 = lane & 15;
    const int b    = blockIdx.z;
    const int o0   = blockIdx.y * 64 + wv * 16;
    const int tok0 = blockIdx.x * 64;

    const __bf16* arow = wqkv + (size_t)(o0 + c16) * CC + g * 8;
    const __bf16* brow = xt + ((size_t)(b * NT + tok0 + c16)) * CC + g * 8;

    f32x4 acc[4];
#pragma unroll
    for (int i = 0; i < 4; ++i) acc[i] = zero4();

#pragma unroll
    for (int k0 = 0; k0 < CC; k0 += 32) {
        bf16x8 a = *(const bf16x8_ma*)(arow + k0);
#pragma unroll
        for (int js = 0; js < 4; ++js) {
            bf16x8 bb = *(const bf16x8_ma*)(brow + (size_t)js * 16 * CC + k0);
            acc[js] = __builtin_amdgcn_mfma_f32_16x16x32_bf16(a, bb, acc[js], 0, 0, 0);
        }
    }

    // o = o0 + g*4 + r ; reg & h are wave/quad-uniform; dd0..dd0+3 consecutive
    const int reg = o0 >> 8;                 // 0=q, 1=k, 2=v (wave-uniform)
    const int oo0 = (o0 & 255) + g * 4;
    const int h   = oo0 >> 5;                // uniform within the quad
    const int dd0 = oo0 & 31;                // multiple of 4
    const size_t bh = (size_t)(b * NHD + h);

#pragma unroll
    for (int js = 0; js < 4; ++js) {
        const int tok = tok0 + js * 16 + c16;
        if (reg == 0) {
            bf16x4 pk;
#pragma unroll
            for (int r = 0; r < 4; ++r) pk[r] = (__bf16)(acc[js][r] * QSCALE);
            *(bf16x4_ma*)(qt + (bh * NT + tok) * HD + dd0) = pk;
        } else if (reg == 1) {
            bf16x4 pk;
#pragma unroll
            for (int r = 0; r < 4; ++r) pk[r] = (__bf16)acc[js][r];
            *(bf16x4_ma*)(kt + (bh * NT + tok) * HD + dd0) = pk;
        } else {
#pragma unroll
            for (int r = 0; r < 4; ++r)
                vv[(bh * HD + dd0 + r) * NT + tok] = (__bf16)acc[js][r];
        }
    }
}

// ---------------------------------------------------------------------------
// Kernel 3: MFMA flash attention, fixed-max softmax, S-TRANSPOSED scores.
// block = 512 threads = 8 waves: wave wv -> query-tile qp = wv&3 (16 rows),
// j-segment seg = wv>>2 (2048 tokens). Additive (O,l) combine via LDS.
// Score MFMA: s = mfma(K_frag, Q_frag) -> D[n=i=c16][m=j=g*4+r]:
// lane holds 4 consecutive j for ONE i -> packed b64 P stores, scalar l.
// grid (NT/64, NB*NHD), block 512.
// ---------------------------------------------------------------------------
__global__ __launch_bounds__(512) void attn_k(const __bf16* __restrict__ qt,
                                              const __bf16* __restrict__ kt,
                                              const __bf16* __restrict__ vv,
                                              __bf16* __restrict__ ao) {
    __shared__ __align__(16) __bf16 P[8][16][76];   // 19.0 KB
    __shared__ float Olds[4][16][33];               //  8.25 KB (seg-1 partials)
    __shared__ float llds[2][4][16];                //  0.5 KB

    const int tid  = threadIdx.x;
    const int lane = tid & 63, wv = tid >> 6;       // wv 0..7
    const int qp = wv & 3, seg = wv >> 2;
    const int g = lane >> 4, c16 = lane & 15;
    const int bh = blockIdx.y;
    const int b = bh >> 3, h = bh & 7;
    const int i0 = blockIdx.x * 64 + qp * 16;

    const __bf16* qbase = qt + ((size_t)bh * NT + i0) * HD;
    const __bf16* kbase = kt + (size_t)bh * NT * HD;
    const __bf16* vbase = vv + (size_t)bh * HD * NT;

    const bf16x8 aq = *(const bf16x8_ma*)(qbase + (size_t)c16 * HD + g * 8);

    f32x4 oacc[2];
    oacc[0] = zero4(); oacc[1] = zero4();
    float rs = 0.f;                                 // l for i = c16 (partial)

    const int j_begin = seg * (NT / 2);
    const int j_end   = j_begin + (NT / 2);

    for (int j0 = j_begin; j0 < j_end; j0 += 64) {
        // ---- scores TRANSPOSED: s[js] = K_tile . Q^T  (D: n=i, m=j) ----
        f32x4 s[4];
#pragma unroll
        for (int js = 0; js < 4; ++js) {
            bf16x8 bk = *(const bf16x8_ma*)(kbase + (size_t)(j0 + js * 16 + c16) * HD + g * 8);
            s[js] = __builtin_amdgcn_mfma_f32_16x16x32_bf16(bk, aq, zero4(), 0, 0, 0);
        }
        // ---- p = exp2(s); l += p; packed b64 store: P[i][js*16+g*4 .. +3] ----
#pragma unroll
        for (int js = 0; js < 4; ++js) {
            bf16x4 pk;
#pragma unroll
            for (int r = 0; r < 4; ++r) {
                const float p = exp2f(s[js][r]);
                rs += p;
                pk[r] = (__bf16)p;
            }
            *(bf16x4_ma*)(&P[wv][c16][js * 16 + g * 4]) = pk;
        }
        // ---- PV: O[i][dd] += P[i][j] * V[dd][j]  (unchanged) ----
#pragma unroll
        for (int ks = 0; ks < 2; ++ks) {
            bf16x8 ap = *(const bf16x8_ma*)(&P[wv][c16][ks * 32 + g * 8]);
#pragma unroll
            for (int t = 0; t < 2; ++t) {
                bf16x8 bv = *(const bf16x8_ma*)(vbase + (size_t)(t * 16 + c16) * NT + j0 + ks * 32 + g * 8);
                oacc[t] = __builtin_amdgcn_mfma_f32_16x16x32_bf16(ap, bv, oacc[t], 0, 0, 0);
            }
        }
    }

    // ---- l: reduce across the 4 quads (j-partitions), then publish ----
    rs += __shfl_xor(rs, 16, 64);
    rs += __shfl_xor(rs, 32, 64);
    if (g == 0) llds[seg][qp][c16] = rs;

    // ---- O partials: seg 1 publishes to LDS ----
    if (seg == 1) {
#pragma unroll
        for (int t = 0; t < 2; ++t)
#pragma unroll
            for (int r = 0; r < 4; ++r)
                Olds[qp][g * 4 + r][t * 16 + c16] = oacc[t][r];
    }
    __syncthreads();

    if (seg == 0) {
        float lf[4];
#pragma unroll
        for (int r = 0; r < 4; ++r)
            lf[r] = llds[0][qp][g * 4 + r] + llds[1][qp][g * 4 + r];
#pragma unroll
        for (int t = 0; t < 2; ++t)
#pragma unroll
            for (int r = 0; r < 4; ++r) {
                const int tok = i0 + g * 4 + r;
                const float v = oacc[t][r] + Olds[qp][g * 4 + r][t * 16 + c16];
                ao[((size_t)(b * NT) + tok) * CC + h * HD + t * 16 + c16] =
                    (__bf16)(v / lf[r]);
            }
    }
}

// ---------------------------------------------------------------------------
// Kernel 4: proj GEMM + residual (MFMA), F32 output.
// grid (NT/64, CC/64, NB), block 256.
// ---------------------------------------------------------------------------
__global__ __launch_bounds__(256) void proj_k(const __bf16* __restrict__ wp,
                                              const __bf16* __restrict__ ao,
                                              const float* __restrict__ x,
                                              float* __restrict__ out) {
    const int lane = threadIdx.x & 63, wv = threadIdx.x >> 6;
    const int g = lane >> 4, c16 = lane & 15;
    const int b    = blockIdx.z;
    const int o0   = blockIdx.y * 64 + wv * 16;
    const int tok0 = blockIdx.x * 64;

    const __bf16* arow = wp + (size_t)(o0 + c16) * CC + g * 8;
    const __bf16* brow = ao + ((size_t)(b * NT + tok0 + c16)) * CC + g * 8;

    f32x4 acc[4];
#pragma unroll
    for (int i = 0; i < 4; ++i) acc[i] = zero4();

#pragma unroll
    for (int k0 = 0; k0 < CC; k0 += 32) {
        bf16x8 a = *(const bf16x8_ma*)(arow + k0);
#pragma unroll
        for (int js = 0; js < 4; ++js) {
            bf16x8 bb = *(const bf16x8_ma*)(brow + (size_t)js * 16 * CC + k0);
            acc[js] = __builtin_amdgcn_mfma_f32_16x16x32_bf16(a, bb, acc[js], 0, 0, 0);
        }
    }

#pragma unroll
    for (int js = 0; js < 4; ++js) {
        const int tok = tok0 + js * 16 + c16;
#pragma unroll
        for (int r = 0; r < 4; ++r) {
            const int o = o0 + g * 4 + r;
            const size_t idx = ((size_t)(b * CC + o)) * NT + tok;
            out[idx] = acc[js][r] + x[idx];
        }
    }
}

// ---------------------------------------------------------------------------
extern "C" void kernel_launch(void* const* d_in, const int* in_sizes, int n_in,
                              void* d_out, int out_size, void* d_ws, size_t ws_size,
                              hipStream_t stream) {
    const int SX  = NB * CC * NT;   // 2,097,152
    const int SW3 = 3 * CC * CC;    //   196,608
    const int SW1 = CC * CC;        //    65,536
    const size_t E = (size_t)SX;

    const float* x  = nullptr;
    const float* wq = nullptr;
    const float* wp = nullptr;
    for (int i = 0; i < n_in; ++i) {
        const int sz = in_sizes[i];
        if (sz == SX || sz == 2 * SX || sz == 4 * SX)           x  = (const float*)d_in[i];
        else if (sz == SW3 || sz == 2 * SW3 || sz == 4 * SW3)   wq = (const float*)d_in[i];
        else if (sz == SW1 || sz == 2 * SW1 || sz == 4 * SW1)   wp = (const float*)d_in[i];
    }
    if (!x || !wq || !wp) {
        x  = (const float*)d_in[0];
        wq = (const float*)d_in[1];
        wp = (const float*)d_in[2];
    }

    // Workspace (bf16 elements), 16.5 MB total (proven):
    __bf16* ws  = (__bf16*)d_ws;
    __bf16* wqb = ws;
    __bf16* wpb = wqb + SW3;
    __bf16* xt  = wpb + SW1;             // becomes ao after qkv_k
    __bf16* qt  = xt + E;
    __bf16* kt  = qt + E;
    __bf16* vv  = kt + E;
    __bf16* ao  = xt;

    float* out = (float*)d_out;

    convw_k<<<dim3(SW3 / 256), 256, 0, stream>>>(wq, wqb, SW3);
    convw_k<<<dim3(SW1 / 256), 256, 0, stream>>>(wp, wpb, SW1);
    transpose_k<<<dim3(NT / 64, CC / 64, NB), 256, 0, stream>>>(x, xt);
    qkv_k<<<dim3(NT / 64, (3 * CC) / 64, NB), 256, 0, stream>>>(wqb, xt, qt, kt, vv);
    attn_k<<<dim3(NT / 64, NB * NHD), 512, 0, stream>>>(qt, kt, vv, ao);
    proj_k<<<dim3(NT / 64, CC / 64, NB), 256, 0, stream>>>(wpb, ao, x, out);
}

// Round 17
// 203.797 us; speedup vs baseline: 1.5667x; 1.5667x over previous
//
#include <hip/hip_runtime.h>
#include <hip/hip_bf16.h>

// Problem constants
#define NB  2      // batch
#define CC  256    // channels
#define NHD 8      // heads
#define HD  32     // head dim
#define NT  4096   // tokens = H*W

typedef __bf16 bf16x8 __attribute__((ext_vector_type(8)));
typedef bf16x8 bf16x8_ma __attribute__((may_alias));
typedef __bf16 bf16x4 __attribute__((ext_vector_type(4)));
typedef bf16x4 bf16x4_ma __attribute__((may_alias));
typedef float  f32x4  __attribute__((ext_vector_type(4)));

static __device__ __forceinline__ f32x4 zero4() {
    f32x4 z = {0.f, 0.f, 0.f, 0.f}; return z;
}

// q pre-scale: log2(e) / sqrt(32)
#define QSCALE 0.25505392421795654f

// ---------------------------------------------------------------------------
// ROUND 17: revert R16's S-transpose (regressed); attack latency with ILP.
// attn_k: wave owns 32 queries (two A-frags) x j-half. Per j-tile: K/V loaded
// ONCE (8 b128), 16 MFMAs through the same softmax neck; two independent
// q-tile streams interleave -> stalls fill with the other tile's work.
// R14 data layout (proven), P stride 76 (R15 conflict fix), exp2/QSCALE.
// ---------------------------------------------------------------------------

// ---------------------------------------------------------------------------
// Kernel 0: f32 -> bf16 convert, both weight arrays in one launch.
// ---------------------------------------------------------------------------
__global__ __launch_bounds__(256) void convw_k(const float* __restrict__ s1,
                                               __bf16* __restrict__ d1, int n1,
                                               const float* __restrict__ s2,
                                               __bf16* __restrict__ d2, int n2) {
    const int i = blockIdx.x * 256 + threadIdx.x;
    if (i < n1) d1[i] = (__bf16)s1[i];
    else if (i - n1 < n2) d2[i - n1] = (__bf16)s2[i - n1];
}

// ---------------------------------------------------------------------------
// Kernel 1: LDS-tiled transpose+convert x f32 [b][c][n] -> xt bf16 [b][n][c].
// ---------------------------------------------------------------------------
__global__ __launch_bounds__(256) void transpose_k(const float* __restrict__ x,
                                                   __bf16* __restrict__ xt) {
    __shared__ __bf16 T[64][65];
    const int tid = threadIdx.x;
    const int n0 = blockIdx.x * 64, c0 = blockIdx.y * 64, b = blockIdx.z;

#pragma unroll
    for (int rep = 0; rep < 16; ++rep) {
        const int e = rep * 256 + tid;
        const int cl = e >> 6, nl = e & 63;
        T[nl][cl] = (__bf16)x[((size_t)(b * CC + c0 + cl)) * NT + n0 + nl];
    }
    __syncthreads();
#pragma unroll
    for (int rep = 0; rep < 16; ++rep) {
        const int e = rep * 256 + tid;
        const int nl = e >> 6, cl = e & 63;
        xt[((size_t)(b * NT + n0 + nl)) * CC + c0 + cl] = T[nl][cl];
    }
}

// ---------------------------------------------------------------------------
// Kernel 2: QKV GEMM (MFMA). q pre-scaled by QSCALE. Packed q/k stores.
// qt/kt token-major [bh][n][32], vv d-major [bh][32][n].
// grid (NT/64, 768/64, NB), block 256.
// ---------------------------------------------------------------------------
__global__ __launch_bounds__(256) void qkv_k(const __bf16* __restrict__ wqkv,
                                             const __bf16* __restrict__ xt,
                                             __bf16* __restrict__ qt,
                                             __bf16* __restrict__ kt,
                                             __bf16* __restrict__ vv) {
    const int lane = threadIdx.x & 63, wv = threadIdx.x >> 6;
    const int g = lane >> 4, c16 = lane & 15;
    const int b    = blockIdx.z;
    const int o0   = blockIdx.y * 64 + wv * 16;
    const int tok0 = blockIdx.x * 64;

    const __bf16* arow = wqkv + (size_t)(o0 + c16) * CC + g * 8;
    const __bf16* brow = xt + ((size_t)(b * NT + tok0 + c16)) * CC + g * 8;

    f32x4 acc[4];
#pragma unroll
    for (int i = 0; i < 4; ++i) acc[i] = zero4();

#pragma unroll
    for (int k0 = 0; k0 < CC; k0 += 32) {
        bf16x8 a = *(const bf16x8_ma*)(arow + k0);
#pragma unroll
        for (int js = 0; js < 4; ++js) {
            bf16x8 bb = *(const bf16x8_ma*)(brow + (size_t)js * 16 * CC + k0);
            acc[js] = __builtin_amdgcn_mfma_f32_16x16x32_bf16(a, bb, acc[js], 0, 0, 0);
        }
    }

    const int reg = o0 >> 8;                 // 0=q, 1=k, 2=v (wave-uniform)
    const int oo0 = (o0 & 255) + g * 4;
    const int h   = oo0 >> 5;
    const int dd0 = oo0 & 31;
    const size_t bh = (size_t)(b * NHD + h);

#pragma unroll
    for (int js = 0; js < 4; ++js) {
        const int tok = tok0 + js * 16 + c16;
        if (reg == 0) {
            bf16x4 pk;
#pragma unroll
            for (int r = 0; r < 4; ++r) pk[r] = (__bf16)(acc[js][r] * QSCALE);
            *(bf16x4_ma*)(qt + (bh * NT + tok) * HD + dd0) = pk;
        } else if (reg == 1) {
            bf16x4 pk;
#pragma unroll
            for (int r = 0; r < 4; ++r) pk[r] = (__bf16)acc[js][r];
            *(bf16x4_ma*)(kt + (bh * NT + tok) * HD + dd0) = pk;
        } else {
#pragma unroll
            for (int r = 0; r < 4; ++r)
                vv[(bh * HD + dd0 + r) * NT + tok] = (__bf16)acc[js][r];
        }
    }
}

// ---------------------------------------------------------------------------
// Kernel 3: MFMA flash attention. Wave = 32 queries (2 A-frags) x j-half.
// Block 256 thr = 4 waves (qp 0/1 x seg 0/1); block covers 64 queries.
// Per j-tile: 4 bk + 4 bv loads shared by both q-tiles; 8 score MFMAs,
// 2x16 exp2 + P stores (R14 layout, stride 76), 8 PV MFMAs.
// Additive (O,l) combine across segs via LDS. grid (NT/64, NB*NHD).
// ---------------------------------------------------------------------------
__global__ __launch_bounds__(256) void attn_k(const __bf16* __restrict__ qt,
                                              const __bf16* __restrict__ kt,
                                              const __bf16* __restrict__ vv,
                                              __bf16* __restrict__ ao) {
    __shared__ __align__(16) __bf16 P[4][2][16][76];   // 19.0 KB
    __shared__ float Olds[2][2][16][33];               //  8.45 KB
    __shared__ float llds[2][2][16];                   //  0.25 KB

    const int tid  = threadIdx.x;
    const int lane = tid & 63, wv = tid >> 6;          // wv 0..3
    const int qp = wv & 1, seg = wv >> 1;
    const int g = lane >> 4, c16 = lane & 15;
    const int bh = blockIdx.y;
    const int b = bh >> 3, h = bh & 7;
    const int i0 = blockIdx.x * 64 + qp * 32;          // this wave: 32 queries

    const __bf16* qbase = qt + ((size_t)bh * NT + i0) * HD;
    const __bf16* kbase = kt + (size_t)bh * NT * HD;
    const __bf16* vbase = vv + (size_t)bh * HD * NT;

    const bf16x8 aq0 = *(const bf16x8_ma*)(qbase + (size_t)c16 * HD + g * 8);
    const bf16x8 aq1 = *(const bf16x8_ma*)(qbase + (size_t)(16 + c16) * HD + g * 8);

    f32x4 oacc[2][2];
#pragma unroll
    for (int qt2 = 0; qt2 < 2; ++qt2)
#pragma unroll
        for (int t = 0; t < 2; ++t) oacc[qt2][t] = zero4();
    float rs[2][4] = {{0.f,0.f,0.f,0.f},{0.f,0.f,0.f,0.f}};

    const int j_begin = seg * (NT / 2);
    const int j_end   = j_begin + (NT / 2);

    for (int j0 = j_begin; j0 < j_end; j0 += 64) {
        // ---- K tile: 4 b128 loads, shared by both q-tiles ----
        bf16x8 bk[4];
#pragma unroll
        for (int js = 0; js < 4; ++js)
            bk[js] = *(const bf16x8_ma*)(kbase + (size_t)(j0 + js * 16 + c16) * HD + g * 8);
        // ---- scores: 8 MFMAs (2 q-tiles x 4 j-sub) ----
        f32x4 s0[4], s1[4];
#pragma unroll
        for (int js = 0; js < 4; ++js)
            s0[js] = __builtin_amdgcn_mfma_f32_16x16x32_bf16(aq0, bk[js], zero4(), 0, 0, 0);
#pragma unroll
        for (int js = 0; js < 4; ++js)
            s1[js] = __builtin_amdgcn_mfma_f32_16x16x32_bf16(aq1, bk[js], zero4(), 0, 0, 0);
        // ---- V tile prefetch: 4 b128, shared by both q-tiles ----
        bf16x8 bv[2][2];
#pragma unroll
        for (int ks = 0; ks < 2; ++ks)
#pragma unroll
            for (int t = 0; t < 2; ++t)
                bv[ks][t] = *(const bf16x8_ma*)(vbase + (size_t)(t * 16 + c16) * NT + j0 + ks * 32 + g * 8);
        // ---- softmax neck: p = exp2(s); P store (R14 layout) ----
#pragma unroll
        for (int js = 0; js < 4; ++js)
#pragma unroll
            for (int r = 0; r < 4; ++r) {
                const float p = exp2f(s0[js][r]);
                rs[0][r] += p;
                P[wv][0][g * 4 + r][js * 16 + c16] = (__bf16)p;
            }
#pragma unroll
        for (int js = 0; js < 4; ++js)
#pragma unroll
            for (int r = 0; r < 4; ++r) {
                const float p = exp2f(s1[js][r]);
                rs[1][r] += p;
                P[wv][1][g * 4 + r][js * 16 + c16] = (__bf16)p;
            }
        // ---- PV: 8 MFMAs ----
#pragma unroll
        for (int ks = 0; ks < 2; ++ks) {
            bf16x8 ap0 = *(const bf16x8_ma*)(&P[wv][0][c16][ks * 32 + g * 8]);
            bf16x8 ap1 = *(const bf16x8_ma*)(&P[wv][1][c16][ks * 32 + g * 8]);
#pragma unroll
            for (int t = 0; t < 2; ++t)
                oacc[0][t] = __builtin_amdgcn_mfma_f32_16x16x32_bf16(ap0, bv[ks][t], oacc[0][t], 0, 0, 0);
#pragma unroll
            for (int t = 0; t < 2; ++t)
                oacc[1][t] = __builtin_amdgcn_mfma_f32_16x16x32_bf16(ap1, bv[ks][t], oacc[1][t], 0, 0, 0);
        }
    }

    // ---- row-sum reduction across the 16 lanes of each group ----
#pragma unroll
    for (int mask = 1; mask <= 8; mask <<= 1)
#pragma unroll
        for (int qt2 = 0; qt2 < 2; ++qt2)
#pragma unroll
            for (int r = 0; r < 4; ++r)
                rs[qt2][r] += __shfl_xor(rs[qt2][r], mask, 64);

    // ---- cross-segment additive combine ----
    if (seg == 1) {
#pragma unroll
        for (int qt2 = 0; qt2 < 2; ++qt2) {
#pragma unroll
            for (int t = 0; t < 2; ++t)
#pragma unroll
                for (int r = 0; r < 4; ++r)
                    Olds[qp][qt2][g * 4 + r][t * 16 + c16] = oacc[qt2][t][r];
            if (c16 == 0)
#pragma unroll
                for (int r = 0; r < 4; ++r)
                    llds[qp][qt2][g * 4 + r] = rs[qt2][r];
        }
    }
    __syncthreads();
    if (seg == 0) {
#pragma unroll
        for (int qt2 = 0; qt2 < 2; ++qt2) {
            float lf[4];
#pragma unroll
            for (int r = 0; r < 4; ++r)
                lf[r] = rs[qt2][r] + llds[qp][qt2][g * 4 + r];
#pragma unroll
            for (int t = 0; t < 2; ++t)
#pragma unroll
                for (int r = 0; r < 4; ++r) {
                    const int tok = i0 + qt2 * 16 + g * 4 + r;
                    const float v = oacc[qt2][t][r] + Olds[qp][qt2][g * 4 + r][t * 16 + c16];
                    ao[((size_t)(b * NT) + tok) * CC + h * HD + t * 16 + c16] =
                        (__bf16)(v / lf[r]);
                }
        }
    }
}

// ---------------------------------------------------------------------------
// Kernel 4: proj GEMM + residual (MFMA), F32 output.
// grid (NT/64, CC/64, NB), block 256.
// ---------------------------------------------------------------------------
__global__ __launch_bounds__(256) void proj_k(const __bf16* __restrict__ wp,
                                              const __bf16* __restrict__ ao,
                                              const float* __restrict__ x,
                                              float* __restrict__ out) {
    const int lane = threadIdx.x & 63, wv = threadIdx.x >> 6;
    const int g = lane >> 4, c16 = lane & 15;
    const int b    = blockIdx.z;
    const int o0   = blockIdx.y * 64 + wv * 16;
    const int tok0 = blockIdx.x * 64;

    const __bf16* arow = wp + (size_t)(o0 + c16) * CC + g * 8;
    const __bf16* brow = ao + ((size_t)(b * NT + tok0 + c16)) * CC + g * 8;

    f32x4 acc[4];
#pragma unroll
    for (int i = 0; i < 4; ++i) acc[i] = zero4();

#pragma unroll
    for (int k0 = 0; k0 < CC; k0 += 32) {
        bf16x8 a = *(const bf16x8_ma*)(arow + k0);
#pragma unroll
        for (int js = 0; js < 4; ++js) {
            bf16x8 bb = *(const bf16x8_ma*)(brow + (size_t)js * 16 * CC + k0);
            acc[js] = __builtin_amdgcn_mfma_f32_16x16x32_bf16(a, bb, acc[js], 0, 0, 0);
        }
    }

#pragma unroll
    for (int js = 0; js < 4; ++js) {
        const int tok = tok0 + js * 16 + c16;
#pragma unroll
        for (int r = 0; r < 4; ++r) {
            const int o = o0 + g * 4 + r;
            const size_t idx = ((size_t)(b * CC + o)) * NT + tok;
            out[idx] = acc[js][r] + x[idx];
        }
    }
}

// ---------------------------------------------------------------------------
extern "C" void kernel_launch(void* const* d_in, const int* in_sizes, int n_in,
                              void* d_out, int out_size, void* d_ws, size_t ws_size,
                              hipStream_t stream) {
    const int SX  = NB * CC * NT;   // 2,097,152
    const int SW3 = 3 * CC * CC;    //   196,608
    const int SW1 = CC * CC;        //    65,536
    const size_t E = (size_t)SX;

    const float* x  = nullptr;
    const float* wq = nullptr;
    const float* wp = nullptr;
    for (int i = 0; i < n_in; ++i) {
        const int sz = in_sizes[i];
        if (sz == SX || sz == 2 * SX || sz == 4 * SX)           x  = (const float*)d_in[i];
        else if (sz == SW3 || sz == 2 * SW3 || sz == 4 * SW3)   wq = (const float*)d_in[i];
        else if (sz == SW1 || sz == 2 * SW1 || sz == 4 * SW1)   wp = (const float*)d_in[i];
    }
    if (!x || !wq || !wp) {
        x  = (const float*)d_in[0];
        wq = (const float*)d_in[1];
        wp = (const float*)d_in[2];
    }

    // Workspace (bf16 elements), 16.5 MB total (proven):
    __bf16* ws  = (__bf16*)d_ws;
    __bf16* wqb = ws;
    __bf16* wpb = wqb + SW3;
    __bf16* xt  = wpb + SW1;             // becomes ao after qkv_k
    __bf16* qt  = xt + E;
    __bf16* kt  = qt + E;
    __bf16* vv  = kt + E;
    __bf16* ao  = xt;

    float* out = (float*)d_out;

    convw_k<<<dim3((SW3 + SW1 + 255) / 256), 256, 0, stream>>>(wq, wqb, SW3, wp, wpb, SW1);
    transpose_k<<<dim3(NT / 64, CC / 64, NB), 256, 0, stream>>>(x, xt);
    qkv_k<<<dim3(NT / 64, (3 * CC) / 64, NB), 256, 0, stream>>>(wqb, xt, qt, kt, vv);
    attn_k<<<dim3(NT / 64, NB * NHD), 256, 0, stream>>>(qt, kt, vv, ao);
    proj_k<<<dim3(NT / 64, CC / 64, NB), 256, 0, stream>>>(wpb, ao, x, out);
}